// Round 1
// baseline (655.094 us; speedup 1.0000x reference)
//
#include <hip/hip_runtime.h>
#include <hip/hip_bf16.h>
#include <stdint.h>

#define N_NODES 50000
#define N_EDGES 1600000
#define D_IN    512
#define D_H1    256   // 4 heads * 64 concat
#define D_OUT   64

typedef __attribute__((ext_vector_type(8))) short  short8;   // 8 bf16 = 4 VGPRs (MFMA A/B frag)
typedef __attribute__((ext_vector_type(4))) float  f32x4;    // MFMA C/D frag
typedef __attribute__((ext_vector_type(4))) unsigned int u32x4;
typedef __attribute__((ext_vector_type(2))) unsigned int u32x2;

static __device__ __forceinline__ unsigned short f2bf(float f) {
    union { float f; unsigned int u; } c; c.f = f;
    unsigned int u = c.u;
    return (unsigned short)((u + 0x7FFFu + ((u >> 16) & 1u)) >> 16);  // RNE
}
static __device__ __forceinline__ float bf2f(unsigned short b) {
    union { unsigned int u; float f; } c; c.u = ((unsigned int)b) << 16;
    return c.f;
}

// ---------------- CSR build: histogram -> scan -> scatter ----------------

__global__ void hist_kernel(const int* __restrict__ src, int* __restrict__ counts) {
    int e = blockIdx.x * blockDim.x + threadIdx.x;
    if (e < N_EDGES) atomicAdd(&counts[src[e]], 1);
}

// single-block 1024-thread Hillis-Steele scan over 50000 counts
__global__ __launch_bounds__(1024) void scan_kernel(const int* __restrict__ counts,
                                                    int* __restrict__ offsets,
                                                    float* __restrict__ invc) {
    __shared__ int buf[1024];
    __shared__ int carry_s;
    int tid = threadIdx.x;
    if (tid == 0) { carry_s = 0; offsets[0] = 0; }
    __syncthreads();
    for (int base = 0; base < N_NODES; base += 1024) {
        int i = base + tid;
        int v = (i < N_NODES) ? counts[i] : 0;
        buf[tid] = v;
        __syncthreads();
        for (int off = 1; off < 1024; off <<= 1) {
            int t = (tid >= off) ? buf[tid - off] : 0;
            __syncthreads();
            buf[tid] += t;
            __syncthreads();
        }
        int incl  = buf[tid];
        int carry = carry_s;
        if (i < N_NODES) {
            offsets[i + 1] = carry + incl;
            invc[i] = (v > 0) ? (1.0f / (float)v) : 0.0f;
        }
        __syncthreads();
        if (tid == 1023) carry_s = carry + buf[1023];
        __syncthreads();
    }
}

__global__ void scatter_kernel(const int* __restrict__ src, const int* __restrict__ dst,
                               const int* __restrict__ offsets, int* __restrict__ cursor,
                               int* __restrict__ sdst) {
    int e = blockIdx.x * blockDim.x + threadIdx.x;
    if (e < N_EDGES) {
        int s = src[e];
        int pos = offsets[s] + atomicAdd(&cursor[s], 1);
        sdst[pos] = dst[e];
    }
}

// ---------------- weight repack (fp32 -> bf16, B transposed: [n][k]) ----------------

__global__ void convw1_kernel(const float* __restrict__ W1, unsigned short* __restrict__ Bt) {
    int i = blockIdx.x * 256 + threadIdx.x;   // over 4*512*64, W1[h][k][j]
    if (i < 4 * 512 * 64) {
        int h = i >> 15;
        int k = (i >> 6) & 511;
        int j = i & 63;
        Bt[(h * 64 + j) * 512 + k] = f2bf(W1[i]);
    }
}
__global__ void convw2_kernel(const float* __restrict__ W2, unsigned short* __restrict__ Bt) {
    int i = blockIdx.x * 256 + threadIdx.x;   // over 256*64, W2[k][n]
    if (i < 256 * 64) {
        int k = i >> 6;
        int n = i & 63;
        Bt[n * 256 + k] = f2bf(W2[i]);
    }
}

// ---------------- bf16 MFMA GEMM: C[M][N] = A[M][K] @ Bt[N][K]^T ----------------
// BM=128, BK=32, block=256 threads (4 waves 2x2), wave tile 64 x (BN/2).
// A is fp32 (converted during staging) or bf16.

template<bool AF32, int BN, int K>
__global__ __launch_bounds__(256) void gemm_kernel(const void* __restrict__ Ap,
                                                   const unsigned short* __restrict__ Bt,
                                                   unsigned short* __restrict__ C,
                                                   int M, int N) {
    constexpr int BM = 128, BK = 32, LDK = 40;   // LDK pad: 80B row stride, 16B-aligned, conflict-cheap
    constexpr int WN = BN / 2, NI = WN / 16;
    __shared__ unsigned short As[BM * LDK];
    __shared__ unsigned short Bs[BN * LDK];

    const int tid  = threadIdx.x;
    const int lane = tid & 63;
    const int w    = tid >> 6;
    const int wm   = (w >> 1) * 64;
    const int wn   = (w & 1) * WN;
    const int quad = lane >> 4;
    const int l15  = lane & 15;
    const int bm   = blockIdx.x;
    const int bn   = blockIdx.y;

    f32x4 acc[4][NI];
#pragma unroll
    for (int mi = 0; mi < 4; ++mi)
#pragma unroll
        for (int ni = 0; ni < NI; ++ni)
            acc[mi][ni] = (f32x4){0.f, 0.f, 0.f, 0.f};

    for (int k0 = 0; k0 < K; k0 += BK) {
        // ---- stage A tile (BM x BK) ----
        if constexpr (AF32) {
            const float* A = (const float*)Ap;
            int f4 = tid & 7;         // 8 float4 per row of 32 k
            int r0 = tid >> 3;        // 32 rows per pass
#pragma unroll
            for (int p = 0; p < 4; ++p) {
                int row  = p * 32 + r0;
                int grow = bm * BM + row;
                f32x4 v = (f32x4){0.f, 0.f, 0.f, 0.f};
                if (grow < M) v = *(const f32x4*)(A + (size_t)grow * K + k0 + f4 * 4);
                u32x2 pk;
                pk[0] = (unsigned int)f2bf(v[0]) | ((unsigned int)f2bf(v[1]) << 16);
                pk[1] = (unsigned int)f2bf(v[2]) | ((unsigned int)f2bf(v[3]) << 16);
                *(u32x2*)&As[row * LDK + f4 * 4] = pk;
            }
        } else {
            const unsigned short* A = (const unsigned short*)Ap;
            int f8 = tid & 3;         // 4 chunks of 8 bf16 per row
            int r0 = tid >> 2;        // 64 rows per pass
#pragma unroll
            for (int p = 0; p < 2; ++p) {
                int row  = p * 64 + r0;
                int grow = bm * BM + row;
                u32x4 v = (u32x4){0u, 0u, 0u, 0u};
                if (grow < M) v = *(const u32x4*)(A + (size_t)grow * K + k0 + f8 * 8);
                *(u32x4*)&As[row * LDK + f8 * 8] = v;
            }
        }
        // ---- stage B tile (BN x BK) from Bt[N][K] ----
        {
            int f8 = tid & 3;
            int r0 = tid >> 2;
#pragma unroll
            for (int p = 0; p < BN / 64; ++p) {
                int row = p * 64 + r0;
                int gn  = bn * BN + row;
                u32x4 v = *(const u32x4*)(Bt + (size_t)gn * K + k0 + f8 * 8);
                *(u32x4*)&Bs[row * LDK + f8 * 8] = v;
            }
        }
        __syncthreads();

        short8 af[4], bfr[NI];
#pragma unroll
        for (int mi = 0; mi < 4; ++mi)
            af[mi] = *(const short8*)&As[(wm + mi * 16 + l15) * LDK + quad * 8];
#pragma unroll
        for (int ni = 0; ni < NI; ++ni)
            bfr[ni] = *(const short8*)&Bs[(wn + ni * 16 + l15) * LDK + quad * 8];
#pragma unroll
        for (int mi = 0; mi < 4; ++mi)
#pragma unroll
            for (int ni = 0; ni < NI; ++ni)
                acc[mi][ni] = __builtin_amdgcn_mfma_f32_16x16x32_bf16(af[mi], bfr[ni], acc[mi][ni], 0, 0, 0);
        __syncthreads();
    }

    // ---- epilogue: C/D layout col=lane&15, row=quad*4+r ----
#pragma unroll
    for (int mi = 0; mi < 4; ++mi) {
        int row0 = bm * BM + wm + mi * 16 + quad * 4;
#pragma unroll
        for (int ni = 0; ni < NI; ++ni) {
            int col = bn * BN + wn + ni * 16 + l15;
#pragma unroll
            for (int r = 0; r < 4; ++r) {
                int row = row0 + r;
                if (row < M) C[(size_t)row * N + col] = f2bf(acc[mi][ni][r]);
            }
        }
    }
}

// ---------------- aggregation (CSR, no atomics) ----------------

// layer 1: one block per node, 256 threads = 256 cols; mean over edges then ELU
__global__ __launch_bounds__(256) void agg1_kernel(const unsigned short* __restrict__ t,
                                                   const int* __restrict__ offs,
                                                   const int* __restrict__ sdst,
                                                   const float* __restrict__ invc,
                                                   unsigned short* __restrict__ h) {
    int s = blockIdx.x;
    int j = threadIdx.x;
    int beg = offs[s], end = offs[s + 1];
    float acc = 0.f;
    int e = beg;
    for (; e + 4 <= end; e += 4) {   // 4-wide ILP on the gather
        int d0 = sdst[e], d1 = sdst[e + 1], d2 = sdst[e + 2], d3 = sdst[e + 3];
        float v0 = bf2f(t[(size_t)d0 * D_H1 + j]);
        float v1 = bf2f(t[(size_t)d1 * D_H1 + j]);
        float v2 = bf2f(t[(size_t)d2 * D_H1 + j]);
        float v3 = bf2f(t[(size_t)d3 * D_H1 + j]);
        acc += (v0 + v1) + (v2 + v3);
    }
    for (; e < end; ++e) acc += bf2f(t[(size_t)sdst[e] * D_H1 + j]);
    float m = acc * invc[s];
    float r = (m > 0.f) ? m : expm1f(m);   // ELU, alpha=1
    h[(size_t)s * D_H1 + j] = f2bf(r);
}

// layer 2: 4 nodes per block (one wave each), 64 cols; mean, fp32 out
__global__ __launch_bounds__(256) void agg2_kernel(const unsigned short* __restrict__ t2,
                                                   const int* __restrict__ offs,
                                                   const int* __restrict__ sdst,
                                                   const float* __restrict__ invc,
                                                   float* __restrict__ out) {
    int s = blockIdx.x * 4 + (threadIdx.x >> 6);
    int j = threadIdx.x & 63;
    if (s >= N_NODES) return;
    int beg = offs[s], end = offs[s + 1];
    float acc = 0.f;
    int e = beg;
    for (; e + 4 <= end; e += 4) {
        int d0 = sdst[e], d1 = sdst[e + 1], d2 = sdst[e + 2], d3 = sdst[e + 3];
        float v0 = bf2f(t2[(size_t)d0 * D_OUT + j]);
        float v1 = bf2f(t2[(size_t)d1 * D_OUT + j]);
        float v2 = bf2f(t2[(size_t)d2 * D_OUT + j]);
        float v3 = bf2f(t2[(size_t)d3 * D_OUT + j]);
        acc += (v0 + v1) + (v2 + v3);
    }
    for (; e < end; ++e) acc += bf2f(t2[(size_t)sdst[e] * D_OUT + j]);
    out[(size_t)s * D_OUT + j] = acc * invc[s];
}

// ---------------- launch ----------------

extern "C" void kernel_launch(void* const* d_in, const int* in_sizes, int n_in,
                              void* d_out, int out_size, void* d_ws, size_t ws_size,
                              hipStream_t stream) {
    const float* X  = (const float*)d_in[0];
    const int*   ei = (const int*)d_in[1];
    const float* W1 = (const float*)d_in[2];
    const float* W2 = (const float*)d_in[3];
    const int* src = ei;             // edge_index[0] = segment ids
    const int* dst = ei + N_EDGES;   // edge_index[1] = gathered neighbors

    char* ws = (char*)d_ws;
    size_t off = 0;
    auto alloc = [&](size_t bytes) {
        off = (off + 255) & ~(size_t)255;
        void* p = ws + off;
        off += bytes;
        return p;
    };
    int*   counts  = (int*)alloc((size_t)N_NODES * 4);
    int*   offsets = (int*)alloc((size_t)(N_NODES + 1) * 4);
    int*   cursor  = (int*)alloc((size_t)N_NODES * 4);
    float* invc    = (float*)alloc((size_t)N_NODES * 4);
    int*   sdst    = (int*)alloc((size_t)N_EDGES * 4);
    unsigned short* Bt1 = (unsigned short*)alloc((size_t)D_H1 * D_IN * 2);
    unsigned short* Bt2 = (unsigned short*)alloc((size_t)D_OUT * D_H1 * 2);
    unsigned short* t1  = (unsigned short*)alloc((size_t)N_NODES * D_H1 * 2);
    unsigned short* h   = (unsigned short*)alloc((size_t)N_NODES * D_H1 * 2);
    unsigned short* t2  = (unsigned short*)alloc((size_t)N_NODES * D_OUT * 2);

    hipMemsetAsync(counts, 0, (size_t)N_NODES * 4, stream);
    hipMemsetAsync(cursor, 0, (size_t)N_NODES * 4, stream);

    hist_kernel<<<(N_EDGES + 255) / 256, 256, 0, stream>>>(src, counts);
    scan_kernel<<<1, 1024, 0, stream>>>(counts, offsets, invc);
    scatter_kernel<<<(N_EDGES + 255) / 256, 256, 0, stream>>>(src, dst, offsets, cursor, sdst);
    convw1_kernel<<<(4 * 512 * 64 + 255) / 256, 256, 0, stream>>>(W1, Bt1);
    convw2_kernel<<<(256 * 64 + 255) / 256, 256, 0, stream>>>(W2, Bt2);

    dim3 g1((N_NODES + 127) / 128, D_H1 / 128);
    gemm_kernel<true, 128, D_IN><<<g1, 256, 0, stream>>>(X, Bt1, t1, N_NODES, D_H1);

    agg1_kernel<<<N_NODES, 256, 0, stream>>>(t1, offsets, sdst, invc, h);

    dim3 g2((N_NODES + 127) / 128, 1);
    gemm_kernel<false, 64, D_H1><<<g2, 256, 0, stream>>>(h, Bt2, t2, N_NODES, D_OUT);

    agg2_kernel<<<N_NODES / 4, 256, 0, stream>>>(t2, offsets, sdst, invc, (float*)d_out);
}

// Round 2
// 523.818 us; speedup vs baseline: 1.2506x; 1.2506x over previous
//
#include <hip/hip_runtime.h>
#include <hip/hip_bf16.h>
#include <stdint.h>

#define N_NODES 50000
#define N_EDGES 1600000
#define D_IN    512
#define D_H1    256   // 4 heads * 64 concat
#define D_OUT   64
#define NB      196   // ceil(50000/256) scan blocks

typedef __attribute__((ext_vector_type(8))) short  short8;   // 8 bf16 = 4 VGPRs (MFMA A/B frag)
typedef __attribute__((ext_vector_type(4))) float  f32x4;    // MFMA C/D frag
typedef __attribute__((ext_vector_type(2))) float  f32x2;
typedef __attribute__((ext_vector_type(4))) unsigned int u32x4;
typedef __attribute__((ext_vector_type(2))) unsigned int u32x2;

static __device__ __forceinline__ unsigned short f2bf(float f) {
    union { float f; unsigned int u; } c; c.f = f;
    unsigned int u = c.u;
    return (unsigned short)((u + 0x7FFFu + ((u >> 16) & 1u)) >> 16);  // RNE
}
static __device__ __forceinline__ float bf2f(unsigned short b) {
    union { unsigned int u; float f; } c; c.u = ((unsigned int)b) << 16;
    return c.f;
}
static __device__ __forceinline__ float bflo(unsigned int v) { return bf2f((unsigned short)(v & 0xffffu)); }
static __device__ __forceinline__ float bfhi(unsigned int v) { return bf2f((unsigned short)(v >> 16)); }

// ---------------- CSR build: histogram -> 3-kernel scan -> scatter ----------------

__global__ void hist_kernel(const int* __restrict__ src, int* __restrict__ counts) {
    int e = blockIdx.x * blockDim.x + threadIdx.x;
    if (e < N_EDGES) atomicAdd(&counts[src[e]], 1);
}

// per-block inclusive scan of 256 counts; block sums out
__global__ __launch_bounds__(256) void scan1_kernel(const int* __restrict__ counts,
                                                    int* __restrict__ offsets,
                                                    float* __restrict__ invc,
                                                    int* __restrict__ blksum) {
    __shared__ int buf[256];
    int t = threadIdx.x;
    int i = blockIdx.x * 256 + t;
    int v = (i < N_NODES) ? counts[i] : 0;
    buf[t] = v;
    __syncthreads();
#pragma unroll
    for (int off = 1; off < 256; off <<= 1) {
        int x = (t >= off) ? buf[t - off] : 0;
        __syncthreads();
        buf[t] += x;
        __syncthreads();
    }
    if (i < N_NODES) {
        offsets[i + 1] = buf[t];                        // block-local inclusive
        invc[i] = (v > 0) ? (1.0f / (float)v) : 0.0f;
    }
    if (t == 255) blksum[blockIdx.x] = buf[255];
}

// single block scans the 196 block sums (inclusive, in place)
__global__ __launch_bounds__(256) void scan2_kernel(int* __restrict__ blksum) {
    __shared__ int buf[256];
    int t = threadIdx.x;
    int v = (t < NB) ? blksum[t] : 0;
    buf[t] = v;
    __syncthreads();
#pragma unroll
    for (int off = 1; off < 256; off <<= 1) {
        int x = (t >= off) ? buf[t - off] : 0;
        __syncthreads();
        buf[t] += x;
        __syncthreads();
    }
    if (t < NB) blksum[t] = buf[t];
}

__global__ __launch_bounds__(256) void scan3_kernel(const int* __restrict__ blksum,
                                                    int* __restrict__ offsets) {
    int b = blockIdx.x, t = threadIdx.x;
    int i = b * 256 + t;
    if (i == 0) offsets[0] = 0;
    if (i < N_NODES && b > 0) offsets[i + 1] += blksum[b - 1];
}

__global__ void scatter_kernel(const int* __restrict__ src, const int* __restrict__ dst,
                               const int* __restrict__ offsets, int* __restrict__ cursor,
                               int* __restrict__ sdst) {
    int e = blockIdx.x * blockDim.x + threadIdx.x;
    if (e < N_EDGES) {
        int s = src[e];
        int pos = offsets[s] + atomicAdd(&cursor[s], 1);
        sdst[pos] = dst[e];
    }
}

// ---------------- weight repack (fp32 -> bf16, B transposed: [n][k]) ----------------

__global__ void convw1_kernel(const float* __restrict__ W1, unsigned short* __restrict__ Bt) {
    int i = blockIdx.x * 256 + threadIdx.x;   // over 4*512*64, W1[h][k][j]
    if (i < 4 * 512 * 64) {
        int h = i >> 15;
        int k = (i >> 6) & 511;
        int j = i & 63;
        Bt[(h * 64 + j) * 512 + k] = f2bf(W1[i]);
    }
}
__global__ void convw2_kernel(const float* __restrict__ W2, unsigned short* __restrict__ Bt) {
    int i = blockIdx.x * 256 + threadIdx.x;   // over 256*64, W2[k][n]
    if (i < 256 * 64) {
        int k = i >> 6;
        int n = i & 63;
        Bt[n * 256 + k] = f2bf(W2[i]);
    }
}

// ---------------- GEMM1: t1[M][256] = X[M][512](fp32) @ Bt1[256][512]^T ----------------
// BM=64, BN=256 (all cols in one pass -> A read once). 4 waves, wave tile 64x64.

__global__ __launch_bounds__(256) void gemm1_kernel(const float* __restrict__ A,
                                                    const unsigned short* __restrict__ Bt,
                                                    unsigned short* __restrict__ C) {
    constexpr int BM = 64, BN = 256, BK = 32, LDK = 40, K = D_IN, M = N_NODES, N = D_H1;
    __shared__ unsigned short As[BM * LDK];
    __shared__ unsigned short Bs[BN * LDK];

    const int tid  = threadIdx.x;
    const int lane = tid & 63;
    const int w    = tid >> 6;
    const int wn   = w * 64;
    const int quad = lane >> 4;
    const int l15  = lane & 15;
    const int bm   = blockIdx.x;

    f32x4 acc[4][4];
#pragma unroll
    for (int mi = 0; mi < 4; ++mi)
#pragma unroll
        for (int ni = 0; ni < 4; ++ni)
            acc[mi][ni] = (f32x4){0.f, 0.f, 0.f, 0.f};

    for (int k0 = 0; k0 < K; k0 += BK) {
        // stage A (64 x 32 fp32 -> bf16)
        {
            int f4 = tid & 7;          // 8 float4 per row
            int r0 = tid >> 3;         // 32 rows per pass
#pragma unroll
            for (int p = 0; p < 2; ++p) {
                int row  = p * 32 + r0;
                int grow = bm * BM + row;
                f32x4 v = (f32x4){0.f, 0.f, 0.f, 0.f};
                if (grow < M) v = *(const f32x4*)(A + (size_t)grow * K + k0 + f4 * 4);
                u32x2 pk;
                pk[0] = (unsigned int)f2bf(v[0]) | ((unsigned int)f2bf(v[1]) << 16);
                pk[1] = (unsigned int)f2bf(v[2]) | ((unsigned int)f2bf(v[3]) << 16);
                *(u32x2*)&As[row * LDK + f4 * 4] = pk;
            }
        }
        // stage B (256 x 32 bf16)
        {
            int f8 = tid & 3;
            int r0 = tid >> 2;         // 64 rows per pass
#pragma unroll
            for (int p = 0; p < 4; ++p) {
                int row = p * 64 + r0;
                u32x4 v = *(const u32x4*)(Bt + (size_t)row * K + k0 + f8 * 8);
                *(u32x4*)&Bs[row * LDK + f8 * 8] = v;
            }
        }
        __syncthreads();

        short8 af[4], bfr[4];
#pragma unroll
        for (int mi = 0; mi < 4; ++mi)
            af[mi] = *(const short8*)&As[(mi * 16 + l15) * LDK + quad * 8];
#pragma unroll
        for (int ni = 0; ni < 4; ++ni)
            bfr[ni] = *(const short8*)&Bs[(wn + ni * 16 + l15) * LDK + quad * 8];
#pragma unroll
        for (int mi = 0; mi < 4; ++mi)
#pragma unroll
            for (int ni = 0; ni < 4; ++ni)
                acc[mi][ni] = __builtin_amdgcn_mfma_f32_16x16x32_bf16(af[mi], bfr[ni], acc[mi][ni], 0, 0, 0);
        __syncthreads();
    }

#pragma unroll
    for (int mi = 0; mi < 4; ++mi) {
        int row0 = bm * BM + mi * 16 + quad * 4;
#pragma unroll
        for (int ni = 0; ni < 4; ++ni) {
            int col = wn + ni * 16 + l15;
#pragma unroll
            for (int r = 0; r < 4; ++r) {
                int row = row0 + r;
                if (row < M) C[(size_t)row * N + col] = f2bf(acc[mi][ni][r]);
            }
        }
    }
}

// ---------------- GEMM2: t2[M][64] = h[M][256](bf16) @ Bt2[64][256]^T ----------------
// BM=128, BN=64, 4 waves 2x2, wave tile 64x32.

__global__ __launch_bounds__(256) void gemm2_kernel(const unsigned short* __restrict__ A,
                                                    const unsigned short* __restrict__ Bt,
                                                    unsigned short* __restrict__ C) {
    constexpr int BM = 128, BN = 64, BK = 32, LDK = 40, K = D_H1, M = N_NODES, N = D_OUT;
    __shared__ unsigned short As[BM * LDK];
    __shared__ unsigned short Bs[BN * LDK];

    const int tid  = threadIdx.x;
    const int lane = tid & 63;
    const int w    = tid >> 6;
    const int wm   = (w >> 1) * 64;
    const int wn   = (w & 1) * 32;
    const int quad = lane >> 4;
    const int l15  = lane & 15;
    const int bm   = blockIdx.x;

    f32x4 acc[4][2];
#pragma unroll
    for (int mi = 0; mi < 4; ++mi)
#pragma unroll
        for (int ni = 0; ni < 2; ++ni)
            acc[mi][ni] = (f32x4){0.f, 0.f, 0.f, 0.f};

    for (int k0 = 0; k0 < K; k0 += BK) {
        {
            int f8 = tid & 3;
            int r0 = tid >> 2;         // 64 rows per pass
#pragma unroll
            for (int p = 0; p < 2; ++p) {
                int row  = p * 64 + r0;
                int grow = bm * BM + row;
                u32x4 v = (u32x4){0u, 0u, 0u, 0u};
                if (grow < M) v = *(const u32x4*)(A + (size_t)grow * K + k0 + f8 * 8);
                *(u32x4*)&As[row * LDK + f8 * 8] = v;
            }
        }
        {
            int f8 = tid & 3;
            int r0 = tid >> 2;
            if (r0 < 64) {
                u32x4 v = *(const u32x4*)(Bt + (size_t)r0 * K + k0 + f8 * 8);
                *(u32x4*)&Bs[r0 * LDK + f8 * 8] = v;
            }
        }
        __syncthreads();

        short8 af[4], bfr[2];
#pragma unroll
        for (int mi = 0; mi < 4; ++mi)
            af[mi] = *(const short8*)&As[(wm + mi * 16 + l15) * LDK + quad * 8];
#pragma unroll
        for (int ni = 0; ni < 2; ++ni)
            bfr[ni] = *(const short8*)&Bs[(wn + ni * 16 + l15) * LDK + quad * 8];
#pragma unroll
        for (int mi = 0; mi < 4; ++mi)
#pragma unroll
            for (int ni = 0; ni < 2; ++ni)
                acc[mi][ni] = __builtin_amdgcn_mfma_f32_16x16x32_bf16(af[mi], bfr[ni], acc[mi][ni], 0, 0, 0);
        __syncthreads();
    }

#pragma unroll
    for (int mi = 0; mi < 4; ++mi) {
        int row0 = bm * BM + wm + mi * 16 + quad * 4;
#pragma unroll
        for (int ni = 0; ni < 2; ++ni) {
            int col = wn + ni * 16 + l15;
#pragma unroll
            for (int r = 0; r < 4; ++r) {
                int row = row0 + r;
                if (row < M) C[(size_t)row * N + col] = f2bf(acc[mi][ni][r]);
            }
        }
    }
}

// ---------------- aggregation (CSR, no atomics, vectorized gathers) ----------------

// layer 1: one WAVE per node; lane j holds cols 4j..4j+3 (8B dwordx2 gather)
__global__ __launch_bounds__(256) void agg1_kernel(const unsigned short* __restrict__ t,
                                                   const int* __restrict__ offs,
                                                   const int* __restrict__ sdst,
                                                   const float* __restrict__ invc,
                                                   unsigned short* __restrict__ h) {
    int s = blockIdx.x * 4 + (threadIdx.x >> 6);
    int j = threadIdx.x & 63;
    int beg = offs[s], end = offs[s + 1];
    const unsigned short* base = t + 4 * j;
    float a0 = 0.f, a1 = 0.f, a2 = 0.f, a3 = 0.f;
    int e = beg;
    for (; e + 4 <= end; e += 4) {
        int d0 = sdst[e], d1 = sdst[e + 1], d2 = sdst[e + 2], d3 = sdst[e + 3];
        u32x2 v0 = *(const u32x2*)(base + (size_t)d0 * D_H1);
        u32x2 v1 = *(const u32x2*)(base + (size_t)d1 * D_H1);
        u32x2 v2 = *(const u32x2*)(base + (size_t)d2 * D_H1);
        u32x2 v3 = *(const u32x2*)(base + (size_t)d3 * D_H1);
        a0 += (bflo(v0[0]) + bflo(v1[0])) + (bflo(v2[0]) + bflo(v3[0]));
        a1 += (bfhi(v0[0]) + bfhi(v1[0])) + (bfhi(v2[0]) + bfhi(v3[0]));
        a2 += (bflo(v0[1]) + bflo(v1[1])) + (bflo(v2[1]) + bflo(v3[1]));
        a3 += (bfhi(v0[1]) + bfhi(v1[1])) + (bfhi(v2[1]) + bfhi(v3[1]));
    }
    for (; e < end; ++e) {
        u32x2 v = *(const u32x2*)(base + (size_t)sdst[e] * D_H1);
        a0 += bflo(v[0]); a1 += bfhi(v[0]); a2 += bflo(v[1]); a3 += bfhi(v[1]);
    }
    float iv = invc[s];
    float m0 = a0 * iv, m1 = a1 * iv, m2 = a2 * iv, m3 = a3 * iv;
    m0 = (m0 > 0.f) ? m0 : expm1f(m0);
    m1 = (m1 > 0.f) ? m1 : expm1f(m1);
    m2 = (m2 > 0.f) ? m2 : expm1f(m2);
    m3 = (m3 > 0.f) ? m3 : expm1f(m3);
    u32x2 pk;
    pk[0] = (unsigned int)f2bf(m0) | ((unsigned int)f2bf(m1) << 16);
    pk[1] = (unsigned int)f2bf(m2) | ((unsigned int)f2bf(m3) << 16);
    *(u32x2*)&h[(size_t)s * D_H1 + 4 * j] = pk;
}

// layer 2: one wave per node; half-waves process alternate edges, u32 (2-col) loads
__global__ __launch_bounds__(256) void agg2_kernel(const unsigned short* __restrict__ t2,
                                                   const int* __restrict__ offs,
                                                   const int* __restrict__ sdst,
                                                   const float* __restrict__ invc,
                                                   float* __restrict__ out) {
    int s = blockIdx.x * 4 + (threadIdx.x >> 6);
    int lane = threadIdx.x & 63;
    int sub = lane >> 5, c = lane & 31;
    int beg = offs[s], end = offs[s + 1];
    const unsigned short* base = t2 + 2 * c;
    float a0 = 0.f, a1 = 0.f;
    int e = beg;
    for (; e + 4 <= end; e += 4) {
        int da = sdst[e + sub], db = sdst[e + 2 + sub];
        unsigned int va = *(const unsigned int*)(base + (size_t)da * D_OUT);
        unsigned int vb = *(const unsigned int*)(base + (size_t)db * D_OUT);
        a0 += bflo(va) + bflo(vb);
        a1 += bfhi(va) + bfhi(vb);
    }
    for (; e + 2 <= end; e += 2) {
        int da = sdst[e + sub];
        unsigned int va = *(const unsigned int*)(base + (size_t)da * D_OUT);
        a0 += bflo(va);
        a1 += bfhi(va);
    }
    if (e < end && sub == 0) {
        unsigned int va = *(const unsigned int*)(base + (size_t)sdst[e] * D_OUT);
        a0 += bflo(va);
        a1 += bfhi(va);
    }
    a0 += __shfl_xor(a0, 32);
    a1 += __shfl_xor(a1, 32);
    if (sub == 0) {
        float iv = invc[s];
        f32x2 r; r[0] = a0 * iv; r[1] = a1 * iv;
        *(f32x2*)(out + (size_t)s * D_OUT + 2 * c) = r;
    }
}

// ---------------- launch ----------------

extern "C" void kernel_launch(void* const* d_in, const int* in_sizes, int n_in,
                              void* d_out, int out_size, void* d_ws, size_t ws_size,
                              hipStream_t stream) {
    const float* X  = (const float*)d_in[0];
    const int*   ei = (const int*)d_in[1];
    const float* W1 = (const float*)d_in[2];
    const float* W2 = (const float*)d_in[3];
    const int* src = ei;             // edge_index[0] = segment ids
    const int* dst = ei + N_EDGES;   // edge_index[1] = gathered neighbors

    char* ws = (char*)d_ws;
    size_t off = 0;
    auto alloc = [&](size_t bytes) {
        off = (off + 255) & ~(size_t)255;
        void* p = ws + off;
        off += bytes;
        return p;
    };
    int*   counts  = (int*)alloc((size_t)N_NODES * 4);
    int*   offsets = (int*)alloc((size_t)(N_NODES + 1) * 4);
    int*   cursor  = (int*)alloc((size_t)N_NODES * 4);
    float* invc    = (float*)alloc((size_t)N_NODES * 4);
    int*   blksum  = (int*)alloc((size_t)NB * 4);
    int*   sdst    = (int*)alloc((size_t)N_EDGES * 4);
    unsigned short* Bt1 = (unsigned short*)alloc((size_t)D_H1 * D_IN * 2);
    unsigned short* Bt2 = (unsigned short*)alloc((size_t)D_OUT * D_H1 * 2);
    unsigned short* t1  = (unsigned short*)alloc((size_t)N_NODES * D_H1 * 2);
    unsigned short* h   = (unsigned short*)alloc((size_t)N_NODES * D_H1 * 2);
    unsigned short* t2  = (unsigned short*)alloc((size_t)N_NODES * D_OUT * 2);

    hipMemsetAsync(counts, 0, (size_t)N_NODES * 4, stream);
    hipMemsetAsync(cursor, 0, (size_t)N_NODES * 4, stream);

    hist_kernel<<<(N_EDGES + 255) / 256, 256, 0, stream>>>(src, counts);
    scan1_kernel<<<NB, 256, 0, stream>>>(counts, offsets, invc, blksum);
    scan2_kernel<<<1, 256, 0, stream>>>(blksum);
    scan3_kernel<<<NB, 256, 0, stream>>>(blksum, offsets);
    scatter_kernel<<<(N_EDGES + 255) / 256, 256, 0, stream>>>(src, dst, offsets, cursor, sdst);
    convw1_kernel<<<(4 * 512 * 64 + 255) / 256, 256, 0, stream>>>(W1, Bt1);
    convw2_kernel<<<(256 * 64 + 255) / 256, 256, 0, stream>>>(W2, Bt2);

    gemm1_kernel<<<(N_NODES + 63) / 64, 256, 0, stream>>>(X, Bt1, t1);
    agg1_kernel<<<N_NODES / 4, 256, 0, stream>>>(t1, offsets, sdst, invc, h);
    gemm2_kernel<<<(N_NODES + 127) / 128, 256, 0, stream>>>(h, Bt2, t2);
    agg2_kernel<<<N_NODES / 4, 256, 0, stream>>>(t2, offsets, sdst, invc, (float*)d_out);
}

// Round 3
// 513.110 us; speedup vs baseline: 1.2767x; 1.0209x over previous
//
#include <hip/hip_runtime.h>
#include <hip/hip_bf16.h>
#include <stdint.h>

#define N_NODES 50000
#define N_EDGES 1600000
#define D_IN    512
#define D_H1    256   // 4 heads * 64 concat
#define D_OUT   64
#define NB      196   // ceil(50000/256) scan blocks

typedef __attribute__((ext_vector_type(8))) short  short8;   // 8 bf16 = 4 VGPRs (MFMA A/B frag)
typedef __attribute__((ext_vector_type(4))) float  f32x4;    // MFMA C/D frag
typedef __attribute__((ext_vector_type(2))) float  f32x2;
typedef __attribute__((ext_vector_type(4))) unsigned int u32x4;
typedef __attribute__((ext_vector_type(2))) unsigned int u32x2;

static __device__ __forceinline__ unsigned short f2bf(float f) {
    union { float f; unsigned int u; } c; c.f = f;
    unsigned int u = c.u;
    return (unsigned short)((u + 0x7FFFu + ((u >> 16) & 1u)) >> 16);  // RNE
}
static __device__ __forceinline__ float bf2f(unsigned short b) {
    union { unsigned int u; float f; } c; c.u = ((unsigned int)b) << 16;
    return c.f;
}
static __device__ __forceinline__ float bflo(unsigned int v) { return bf2f((unsigned short)(v & 0xffffu)); }
static __device__ __forceinline__ float bfhi(unsigned int v) { return bf2f((unsigned short)(v >> 16)); }

// ---------------- CSR build: histogram -> 3-kernel scan -> scatter ----------------

__global__ void hist_kernel(const int* __restrict__ src, int* __restrict__ counts) {
    int e = blockIdx.x * blockDim.x + threadIdx.x;
    if (e < N_EDGES) atomicAdd(&counts[src[e]], 1);
}

__global__ __launch_bounds__(256) void scan1_kernel(const int* __restrict__ counts,
                                                    int* __restrict__ offsets,
                                                    float* __restrict__ invc,
                                                    int* __restrict__ blksum) {
    __shared__ int buf[256];
    int t = threadIdx.x;
    int i = blockIdx.x * 256 + t;
    int v = (i < N_NODES) ? counts[i] : 0;
    buf[t] = v;
    __syncthreads();
#pragma unroll
    for (int off = 1; off < 256; off <<= 1) {
        int x = (t >= off) ? buf[t - off] : 0;
        __syncthreads();
        buf[t] += x;
        __syncthreads();
    }
    if (i < N_NODES) {
        offsets[i + 1] = buf[t];                        // block-local inclusive
        invc[i] = (v > 0) ? (1.0f / (float)v) : 0.0f;
    }
    if (t == 255) blksum[blockIdx.x] = buf[255];
}

__global__ __launch_bounds__(256) void scan2_kernel(int* __restrict__ blksum) {
    __shared__ int buf[256];
    int t = threadIdx.x;
    int v = (t < NB) ? blksum[t] : 0;
    buf[t] = v;
    __syncthreads();
#pragma unroll
    for (int off = 1; off < 256; off <<= 1) {
        int x = (t >= off) ? buf[t - off] : 0;
        __syncthreads();
        buf[t] += x;
        __syncthreads();
    }
    if (t < NB) blksum[t] = buf[t];
}

__global__ __launch_bounds__(256) void scan3_kernel(const int* __restrict__ blksum,
                                                    int* __restrict__ offsets) {
    int b = blockIdx.x, t = threadIdx.x;
    int i = b * 256 + t;
    if (i == 0) offsets[0] = 0;
    if (i < N_NODES && b > 0) offsets[i + 1] += blksum[b - 1];
}

__global__ void scatter_kernel(const int* __restrict__ src, const int* __restrict__ dst,
                               const int* __restrict__ offsets, int* __restrict__ cursor,
                               int* __restrict__ sdst) {
    int e = blockIdx.x * blockDim.x + threadIdx.x;
    if (e < N_EDGES) {
        int s = src[e];
        int pos = offsets[s] + atomicAdd(&cursor[s], 1);
        sdst[pos] = dst[e];
    }
}

// ---------------- weight repack (fused, fp32 -> bf16, B transposed: [n][k]) ----------------

__global__ void convw_kernel(const float* __restrict__ W1, const float* __restrict__ W2,
                             unsigned short* __restrict__ Bt1, unsigned short* __restrict__ Bt2) {
    int i = blockIdx.x * 256 + threadIdx.x;
    if (i < 4 * 512 * 64) {                 // W1[h][k][j] -> Bt1[(h*64+j)][k]
        int h = i >> 15;
        int k = (i >> 6) & 511;
        int j = i & 63;
        Bt1[(h * 64 + j) * 512 + k] = f2bf(W1[i]);
    } else {
        int r = i - 4 * 512 * 64;           // W2[k][n] -> Bt2[n][k]
        if (r < 256 * 64) {
            int k = r >> 6;
            int n = r & 63;
            Bt2[n * 256 + k] = f2bf(W2[r]);
        }
    }
}

// ---------------- GEMM1: t1[M][256] = X[M][512](fp32) @ Bt1[256][512]^T ----------------

__global__ __launch_bounds__(256) void gemm1_kernel(const float* __restrict__ A,
                                                    const unsigned short* __restrict__ Bt,
                                                    unsigned short* __restrict__ C) {
    constexpr int BM = 64, BN = 256, BK = 32, LDK = 40, K = D_IN, M = N_NODES, N = D_H1;
    __shared__ unsigned short As[BM * LDK];
    __shared__ unsigned short Bs[BN * LDK];

    const int tid  = threadIdx.x;
    const int lane = tid & 63;
    const int w    = tid >> 6;
    const int wn   = w * 64;
    const int quad = lane >> 4;
    const int l15  = lane & 15;
    const int bm   = blockIdx.x;

    f32x4 acc[4][4];
#pragma unroll
    for (int mi = 0; mi < 4; ++mi)
#pragma unroll
        for (int ni = 0; ni < 4; ++ni)
            acc[mi][ni] = (f32x4){0.f, 0.f, 0.f, 0.f};

    for (int k0 = 0; k0 < K; k0 += BK) {
        {
            int f4 = tid & 7;
            int r0 = tid >> 3;
#pragma unroll
            for (int p = 0; p < 2; ++p) {
                int row  = p * 32 + r0;
                int grow = bm * BM + row;
                f32x4 v = (f32x4){0.f, 0.f, 0.f, 0.f};
                if (grow < M) v = *(const f32x4*)(A + (size_t)grow * K + k0 + f4 * 4);
                u32x2 pk;
                pk[0] = (unsigned int)f2bf(v[0]) | ((unsigned int)f2bf(v[1]) << 16);
                pk[1] = (unsigned int)f2bf(v[2]) | ((unsigned int)f2bf(v[3]) << 16);
                *(u32x2*)&As[row * LDK + f4 * 4] = pk;
            }
        }
        {
            int f8 = tid & 3;
            int r0 = tid >> 2;
#pragma unroll
            for (int p = 0; p < 4; ++p) {
                int row = p * 64 + r0;
                u32x4 v = *(const u32x4*)(Bt + (size_t)row * K + k0 + f8 * 8);
                *(u32x4*)&Bs[row * LDK + f8 * 8] = v;
            }
        }
        __syncthreads();

        short8 af[4], bfr[4];
#pragma unroll
        for (int mi = 0; mi < 4; ++mi)
            af[mi] = *(const short8*)&As[(mi * 16 + l15) * LDK + quad * 8];
#pragma unroll
        for (int ni = 0; ni < 4; ++ni)
            bfr[ni] = *(const short8*)&Bs[(wn + ni * 16 + l15) * LDK + quad * 8];
#pragma unroll
        for (int mi = 0; mi < 4; ++mi)
#pragma unroll
            for (int ni = 0; ni < 4; ++ni)
                acc[mi][ni] = __builtin_amdgcn_mfma_f32_16x16x32_bf16(af[mi], bfr[ni], acc[mi][ni], 0, 0, 0);
        __syncthreads();
    }

#pragma unroll
    for (int mi = 0; mi < 4; ++mi) {
        int row0 = bm * BM + mi * 16 + quad * 4;
#pragma unroll
        for (int ni = 0; ni < 4; ++ni) {
            int col = wn + ni * 16 + l15;
#pragma unroll
            for (int r = 0; r < 4; ++r) {
                int row = row0 + r;
                if (row < M) C[(size_t)row * N + col] = f2bf(acc[mi][ni][r]);
            }
        }
    }
}

// ---------------- GEMM2: t2[M][64] = h[M][256](bf16) @ Bt2[64][256]^T ----------------
// BM=64 (782 blocks for CU balance), 4 waves 2x2, wave tile 32x32.

__global__ __launch_bounds__(256) void gemm2_kernel(const unsigned short* __restrict__ A,
                                                    const unsigned short* __restrict__ Bt,
                                                    unsigned short* __restrict__ C) {
    constexpr int BM = 64, BN = 64, BK = 32, LDK = 40, K = D_H1, M = N_NODES, N = D_OUT;
    __shared__ unsigned short As[BM * LDK];
    __shared__ unsigned short Bs[BN * LDK];

    const int tid  = threadIdx.x;
    const int lane = tid & 63;
    const int w    = tid >> 6;
    const int wm   = (w >> 1) * 32;
    const int wn   = (w & 1) * 32;
    const int quad = lane >> 4;
    const int l15  = lane & 15;
    const int bm   = blockIdx.x;

    f32x4 acc[2][2];
#pragma unroll
    for (int mi = 0; mi < 2; ++mi)
#pragma unroll
        for (int ni = 0; ni < 2; ++ni)
            acc[mi][ni] = (f32x4){0.f, 0.f, 0.f, 0.f};

    for (int k0 = 0; k0 < K; k0 += BK) {
        {
            int f8 = tid & 3;
            int r0 = tid >> 2;
            int grow = bm * BM + r0;
            u32x4 v = (u32x4){0u, 0u, 0u, 0u};
            if (grow < M) v = *(const u32x4*)(A + (size_t)grow * K + k0 + f8 * 8);
            *(u32x4*)&As[r0 * LDK + f8 * 8] = v;
        }
        {
            int f8 = tid & 3;
            int r0 = tid >> 2;
            u32x4 v = *(const u32x4*)(Bt + (size_t)r0 * K + k0 + f8 * 8);
            *(u32x4*)&Bs[r0 * LDK + f8 * 8] = v;
        }
        __syncthreads();

        short8 af[2], bfr[2];
#pragma unroll
        for (int mi = 0; mi < 2; ++mi)
            af[mi] = *(const short8*)&As[(wm + mi * 16 + l15) * LDK + quad * 8];
#pragma unroll
        for (int ni = 0; ni < 2; ++ni)
            bfr[ni] = *(const short8*)&Bs[(wn + ni * 16 + l15) * LDK + quad * 8];
#pragma unroll
        for (int mi = 0; mi < 2; ++mi)
#pragma unroll
            for (int ni = 0; ni < 2; ++ni)
                acc[mi][ni] = __builtin_amdgcn_mfma_f32_16x16x32_bf16(af[mi], bfr[ni], acc[mi][ni], 0, 0, 0);
        __syncthreads();
    }

#pragma unroll
    for (int mi = 0; mi < 2; ++mi) {
        int row0 = bm * BM + wm + mi * 16 + quad * 4;
#pragma unroll
        for (int ni = 0; ni < 2; ++ni) {
            int col = wn + ni * 16 + l15;
#pragma unroll
            for (int r = 0; r < 4; ++r) {
                int row = row0 + r;
                if (row < M) C[(size_t)row * N + col] = f2bf(acc[mi][ni][r]);
            }
        }
    }
}

// ---------------- aggregation (CSR, no atomics, 16B vector gathers) ----------------

// layer 1: one wave per node; half-wave (32 lanes x 16B) covers a full 512B t1 row,
// 2 edges in flight per wave, 8-edge unroll (4 outstanding dwordx4 per lane).
__global__ __launch_bounds__(256) void agg1_kernel(const unsigned short* __restrict__ t,
                                                   const int* __restrict__ offs,
                                                   const int* __restrict__ sdst,
                                                   const float* __restrict__ invc,
                                                   unsigned short* __restrict__ h) {
    int s = __builtin_amdgcn_readfirstlane(blockIdx.x * 4 + (threadIdx.x >> 6));
    int lane = threadIdx.x & 63;
    int sub = lane >> 5;         // which of 2 concurrent edges
    int c   = lane & 31;         // 8 cols per lane: 8c..8c+7
    int beg = offs[s], end = offs[s + 1];
    const unsigned short* base = t + 8 * c;

    float a[8];
#pragma unroll
    for (int k = 0; k < 8; ++k) a[k] = 0.f;

    int e = beg;
    for (; e + 8 <= end; e += 8) {
        int i0 = sdst[e + 0 + sub], i1 = sdst[e + 2 + sub];
        int i2 = sdst[e + 4 + sub], i3 = sdst[e + 6 + sub];
        u32x4 v0 = *(const u32x4*)(base + (size_t)i0 * D_H1);
        u32x4 v1 = *(const u32x4*)(base + (size_t)i1 * D_H1);
        u32x4 v2 = *(const u32x4*)(base + (size_t)i2 * D_H1);
        u32x4 v3 = *(const u32x4*)(base + (size_t)i3 * D_H1);
#pragma unroll
        for (int q = 0; q < 4; ++q) {
            a[2 * q]     += (bflo(v0[q]) + bflo(v1[q])) + (bflo(v2[q]) + bflo(v3[q]));
            a[2 * q + 1] += (bfhi(v0[q]) + bfhi(v1[q])) + (bfhi(v2[q]) + bfhi(v3[q]));
        }
    }
    for (; e + 2 <= end; e += 2) {
        int i0 = sdst[e + sub];
        u32x4 v = *(const u32x4*)(base + (size_t)i0 * D_H1);
#pragma unroll
        for (int q = 0; q < 4; ++q) {
            a[2 * q]     += bflo(v[q]);
            a[2 * q + 1] += bfhi(v[q]);
        }
    }
    if (e < end && sub == 0) {
        int i0 = sdst[e];
        u32x4 v = *(const u32x4*)(base + (size_t)i0 * D_H1);
#pragma unroll
        for (int q = 0; q < 4; ++q) {
            a[2 * q]     += bflo(v[q]);
            a[2 * q + 1] += bfhi(v[q]);
        }
    }
#pragma unroll
    for (int k = 0; k < 8; ++k) a[k] += __shfl_xor(a[k], 32);

    if (sub == 0) {
        float iv = invc[s];
        u32x4 pk;
#pragma unroll
        for (int q = 0; q < 4; ++q) {
            float m0 = a[2 * q] * iv, m1 = a[2 * q + 1] * iv;
            m0 = (m0 > 0.f) ? m0 : (__expf(m0) - 1.f);
            m1 = (m1 > 0.f) ? m1 : (__expf(m1) - 1.f);
            pk[q] = (unsigned int)f2bf(m0) | ((unsigned int)f2bf(m1) << 16);
        }
        *(u32x4*)&h[(size_t)s * D_H1 + 8 * c] = pk;
    }
}

// layer 2: one wave per node; quarter-wave (16 lanes x 8B) covers a full 128B t2 row,
// 4 edges in flight per wave, 8-edge unroll.
__global__ __launch_bounds__(256) void agg2_kernel(const unsigned short* __restrict__ t2,
                                                   const int* __restrict__ offs,
                                                   const int* __restrict__ sdst,
                                                   const float* __restrict__ invc,
                                                   float* __restrict__ out) {
    int s = __builtin_amdgcn_readfirstlane(blockIdx.x * 4 + (threadIdx.x >> 6));
    int lane = threadIdx.x & 63;
    int sub = lane >> 4;         // which of 4 concurrent edges
    int c   = lane & 15;         // 4 cols per lane: 4c..4c+3
    int beg = offs[s], end = offs[s + 1];
    const unsigned short* base = t2 + 4 * c;

    float a0 = 0.f, a1 = 0.f, a2 = 0.f, a3 = 0.f;
    int e = beg;
    for (; e + 8 <= end; e += 8) {
        int i0 = sdst[e + sub], i1 = sdst[e + 4 + sub];
        u32x2 v0 = *(const u32x2*)(base + (size_t)i0 * D_OUT);
        u32x2 v1 = *(const u32x2*)(base + (size_t)i1 * D_OUT);
        a0 += bflo(v0[0]) + bflo(v1[0]);
        a1 += bfhi(v0[0]) + bfhi(v1[0]);
        a2 += bflo(v0[1]) + bflo(v1[1]);
        a3 += bfhi(v0[1]) + bfhi(v1[1]);
    }
    for (; e + 4 <= end; e += 4) {
        int i0 = sdst[e + sub];
        u32x2 v = *(const u32x2*)(base + (size_t)i0 * D_OUT);
        a0 += bflo(v[0]); a1 += bfhi(v[0]); a2 += bflo(v[1]); a3 += bfhi(v[1]);
    }
    int rem = end - e;
    if (sub < rem) {
        int i0 = sdst[e + sub];
        u32x2 v = *(const u32x2*)(base + (size_t)i0 * D_OUT);
        a0 += bflo(v[0]); a1 += bfhi(v[0]); a2 += bflo(v[1]); a3 += bfhi(v[1]);
    }
    a0 += __shfl_xor(a0, 16); a1 += __shfl_xor(a1, 16);
    a2 += __shfl_xor(a2, 16); a3 += __shfl_xor(a3, 16);
    a0 += __shfl_xor(a0, 32); a1 += __shfl_xor(a1, 32);
    a2 += __shfl_xor(a2, 32); a3 += __shfl_xor(a3, 32);
    if (sub == 0) {
        float iv = invc[s];
        f32x4 r; r[0] = a0 * iv; r[1] = a1 * iv; r[2] = a2 * iv; r[3] = a3 * iv;
        *(f32x4*)(out + (size_t)s * D_OUT + 4 * c) = r;
    }
}

// ---------------- launch ----------------

extern "C" void kernel_launch(void* const* d_in, const int* in_sizes, int n_in,
                              void* d_out, int out_size, void* d_ws, size_t ws_size,
                              hipStream_t stream) {
    const float* X  = (const float*)d_in[0];
    const int*   ei = (const int*)d_in[1];
    const float* W1 = (const float*)d_in[2];
    const float* W2 = (const float*)d_in[3];
    const int* src = ei;             // edge_index[0] = segment ids
    const int* dst = ei + N_EDGES;   // edge_index[1] = gathered neighbors

    char* ws = (char*)d_ws;
    size_t off = 0;
    auto alloc = [&](size_t bytes) {
        off = (off + 255) & ~(size_t)255;
        void* p = ws + off;
        off += bytes;
        return p;
    };
    int*   counts  = (int*)alloc((size_t)N_NODES * 4);
    int*   offsets = (int*)alloc((size_t)(N_NODES + 1) * 4);
    int*   cursor  = (int*)alloc((size_t)N_NODES * 4);
    float* invc    = (float*)alloc((size_t)N_NODES * 4);
    int*   blksum  = (int*)alloc((size_t)NB * 4);
    int*   sdst    = (int*)alloc((size_t)N_EDGES * 4);
    unsigned short* Bt1 = (unsigned short*)alloc((size_t)D_H1 * D_IN * 2);
    unsigned short* Bt2 = (unsigned short*)alloc((size_t)D_OUT * D_H1 * 2);
    unsigned short* t1  = (unsigned short*)alloc((size_t)N_NODES * D_H1 * 2);
    unsigned short* h   = (unsigned short*)alloc((size_t)N_NODES * D_H1 * 2);
    unsigned short* t2  = (unsigned short*)alloc((size_t)N_NODES * D_OUT * 2);

    hipMemsetAsync(counts, 0, (size_t)N_NODES * 4, stream);
    hipMemsetAsync(cursor, 0, (size_t)N_NODES * 4, stream);

    hist_kernel<<<(N_EDGES + 255) / 256, 256, 0, stream>>>(src, counts);
    scan1_kernel<<<NB, 256, 0, stream>>>(counts, offsets, invc, blksum);
    scan2_kernel<<<1, 256, 0, stream>>>(blksum);
    scan3_kernel<<<NB, 256, 0, stream>>>(blksum, offsets);
    scatter_kernel<<<(N_EDGES + 255) / 256, 256, 0, stream>>>(src, dst, offsets, cursor, sdst);
    convw_kernel<<<(4 * 512 * 64 + 256 * 64 + 255) / 256, 256, 0, stream>>>(W1, W2, Bt1, Bt2);

    gemm1_kernel<<<(N_NODES + 63) / 64, 256, 0, stream>>>(X, Bt1, t1);
    agg1_kernel<<<N_NODES / 4, 256, 0, stream>>>(t1, offsets, sdst, invc, h);
    gemm2_kernel<<<(N_NODES + 63) / 64, 256, 0, stream>>>(h, Bt2, t2);
    agg2_kernel<<<N_NODES / 4, 256, 0, stream>>>(t2, offsets, sdst, invc, (float*)d_out);
}